// Round 3
// baseline (3135.626 us; speedup 1.0000x reference)
//
#include <hip/hip_runtime.h>
#include <math.h>

typedef float  fx4  __attribute__((ext_vector_type(4)));
typedef short  bfx8 __attribute__((ext_vector_type(8)));

// Bilinear weights exactly mirroring the reference resize_bilinear.
__device__ __forceinline__ void bl_w(int o, int O, int I, int& i0, int& i1, float& w) {
    float r = (float)((double)I / (double)O);
    float f = (o + 0.5f) * r - 0.5f;
    f = fminf(fmaxf(f, 0.0f), (float)(I - 1));
    int a = (int)floorf(f);
    i0 = a;
    i1 = min(a + 1, I - 1);
    w = f - (float)a;
}

__device__ __forceinline__ unsigned int bf16rne(float f) {
    unsigned int x = __builtin_bit_cast(unsigned int, f);
    return ((x + 0x7fffu + ((x >> 16) & 1u)) >> 16) & 0xffffu;
}

// Meta: per (b,lvl): [0]=mh [1]=mw ; [2+4n..]=t,l,ch,cw ; [2+4N+2s..]=fh,fw (s=1.0,0.9,1.1)
__global__ void k_meta(const int* __restrict__ tlbr, const int* __restrict__ p_imgh,
                       const int* __restrict__ p_imgw, int B, int N, int ms,
                       int* __restrict__ meta) {
    if (blockIdx.x != 0 || threadIdx.x != 0) return;
    const int HFs[2] = {128, 64};
    const double SC[2] = {0.9, 1.1};
    int img_h = *p_imgh, img_w = *p_imgw;
    for (int b = 0; b < B; ++b)
      for (int lvl = 0; lvl < 2; ++lvl) {
        int HF = HFs[lvl], WF = HFs[lvl];
        double sh = (double)HF / (double)img_h;
        double sw = (double)WF / (double)img_w;
        int* m = meta + (b*2 + lvl)*ms;
        int mh = 0, mw = 0;
        for (int n = 0; n < N; ++n) {
            const int* bx = tlbr + ((size_t)(b*N) + n)*4;
            int t  = max((int)floor((double)bx[0]*sh), 0);
            int l  = max((int)floor((double)bx[1]*sw), 0);
            int bb = min((int)ceil((double)bx[2]*sh) + 1, HF);
            int rr = min((int)ceil((double)bx[3]*sw) + 1, WF);
            int chh = bb - t, cww = rr - l;
            m[2+4*n+0] = t; m[2+4*n+1] = l; m[2+4*n+2] = chh; m[2+4*n+3] = cww;
            mh = max(mh, chh); mw = max(mw, cww);
        }
        m[0] = mh; m[1] = mw;
        int fo = 2 + 4*N;
        m[fo+0] = mh; m[fo+1] = mw;
        for (int s = 0; s < 2; ++s) {
            int hs  = (int)ceil((double)mh * SC[s]); if (hs  <= 1) hs  = mh;
            int wsv = (int)ceil((double)mw * SC[s]); if (wsv <= 1) wsv = mw;
            m[fo+2+2*s] = hs; m[fo+2+2*s+1] = wsv;
        }
      }
}

// Crop -> (mh,mw) fp32 patches.
__global__ void k_patches(const float* __restrict__ feat_all, int C, int HF, int WF,
                          float* __restrict__ patches, int MH, int MW,
                          int B, int N, int lvl, int ms, const int* __restrict__ meta) {
    long long idx = (long long)blockIdx.x * blockDim.x + threadIdx.x;
    long long total = (long long)B * N * C * MH * MW;
    if (idx >= total) return;
    int px = (int)(idx % MW); long long r = idx / MW;
    int py = (int)(r % MH); r /= MH;
    int c  = (int)(r % C);  r /= C;
    int n  = (int)(r % N);
    int b  = (int)(r / N);
    const int* m = meta + (b*2 + lvl)*ms;
    int mh = m[0], mw = m[1];
    if (py >= mh || px >= mw) return;
    int t = m[2+4*n], l = m[3+4*n], chh = m[4+4*n], cww = m[5+4*n];
    int y0, y1, x0, x1; float wy, wx;
    bl_w(py, mh, chh, y0, y1, wy);
    bl_w(px, mw, cww, x0, x1, wx);
    const float* src = feat_all + ((size_t)b * C + c) * HF * WF;
    float f00 = src[(t + y0) * WF + (l + x0)];
    float f10 = src[(t + y1) * WF + (l + x0)];
    float f01 = src[(t + y0) * WF + (l + x1)];
    float f11 = src[(t + y1) * WF + (l + x1)];
    float v = (f00 * (1.f - wy) + f10 * wy) * (1.f - wx)
            + (f01 * (1.f - wy) + f11 * wy) * wx;
    patches[(((size_t)(b*N + n) * C + c) * MH + py) * MW + px] = v;
}

// Build bf16 filters, zero-embedded in KHxKW canvas, directly in MFMA A-frag
// swizzled order: u32 pair index = (((lb*KT + kt)*4 + g)*16 + m)*4 + jj/2,
// where k = kt*32 + g*8 + jj, k = c*KH*KW + kx*KH + ky (ky innermost!).
template<int C, int KH, int KW, int MH, int MW>
__global__ void k_filters(const float* __restrict__ patches, const int* __restrict__ meta,
                          unsigned short* __restrict__ Wswz, int b0, int chunkB,
                          int N, int lvl, int ms) {
    constexpr int KHW = KH*KW;
    constexpr int KT  = C*KHW/32;
    long long idx = (long long)blockIdx.x*256 + threadIdx.x;
    long long total = (long long)chunkB * KT * 256;   // u32 pairs
    if (idx >= total) return;
    int jj = ((int)(idx & 3)) * 2;
    int m  = (int)((idx >> 2) & 15);
    int g  = (int)((idx >> 6) & 3);
    long long rest = idx >> 8;
    int kt = (int)(rest % KT);
    int lb = (int)(rest / KT);
    unsigned int outv = 0;
    int sc = m / N, n = m - sc*N;
    if (sc < 3) {
        int b = b0 + lb;
        const int* mt = meta + (b*2 + lvl)*ms;
        int mh = mt[0], mw = mt[1];
        int fo = 2 + 4*N;
        int fh = mt[fo + 2*sc], fw = mt[fo + 2*sc + 1];
        int offy = KH/2 - fh/2, offx = KW/2 - fw/2;
        int k = kt*32 + g*8 + jj;
        int c = k / KHW; int rem = k - c*KHW;
        int kx = rem / KH; int ky = rem - kx*KH;
        int fx = kx - offx;
        if (fx >= 0 && fx < fw) {
            const float* pat = patches + ((size_t)(b*N + n)*C + c)*(MH*MW);
            int x0,x1,y0,y1; float wx,wy;
            bl_w(fx, fw, mw, x0, x1, wx);
            #pragma unroll
            for (int q = 0; q < 2; ++q) {
                int fy = ky + q - offy;
                if (fy >= 0 && fy < fh) {
                    bl_w(fy, fh, mh, y0, y1, wy);
                    float v = (pat[y0*MW+x0]*(1.f-wy) + pat[y1*MW+x0]*wy)*(1.f-wx)
                            + (pat[y0*MW+x1]*(1.f-wy) + pat[y1*MW+x1]*wy)*wx;
                    outv |= bf16rne(v) << (16*q);
                }
            }
        }
    }
    ((unsigned int*)Wswz)[idx] = outv;
}

// MFMA implicit-GEMM xcorr. Block = one output row (W pixels), 4 waves,
// NT N-tiles of 16 pixels per wave. Feature tile staged column-major bf16 in
// LDS: 48-byte columns (24 ky slots = odd multiple of 16B -> conflict-free
// ds_read_b128 across pixels), rt-fastest staging -> contiguous ds_write.
template<int C, int KH, int KW, int H, int W, int CC, int NT, int NCOLP, int P>
__global__ __launch_bounds__(256, 4) void k_mfconv(
        const float* __restrict__ feat_all, const unsigned short* __restrict__ Wswz,
        float* __restrict__ dst, int b0, int N, int planes) {
    constexpr int KHW    = KH*KW;
    constexpr int KSC    = KHW/32;          // K-steps per channel
    constexpr int NKK    = CC*KSC;          // K-steps per staged chunk
    constexpr int RSTR   = 24;              // LDS rows per column (48B)
    constexpr int CHSTRB = NCOLP*RSTR*2;    // LDS bytes per channel (mult of 128)
    constexpr int NCT    = NCOLP/4;
    constexpr int NROWT  = 6;               // 24 LDS rows / 4
    constexpr int KT     = C*KSC;
    __shared__ __align__(16) unsigned char smem[CC*CHSTRB + NKK*16];
    unsigned int* tbl = (unsigned int*)(smem + CC*CHSTRB);

    const int y0  = blockIdx.x;
    const int lb  = blockIdx.y;
    const int b   = b0 + lb;
    const int tid = threadIdx.x;
    const int lane = tid & 63;
    const int wv   = tid >> 6;
    const int g    = lane >> 4;
    const int lm   = lane & 15;

    for (int e = tid; e < NKK*4; e += 256) {
        int kk = e >> 2, gg = e & 3;
        int kb = kk*32 + gg*8;
        int cof = kb / KHW; int rem = kb - cof*KHW;
        int kx = rem / KH;  int ky = rem - kx*KH;
        tbl[e] = (unsigned int)(cof*CHSTRB + (kx*RSTR + ky)*2);
    }

    fx4 acc[NT];
    #pragma unroll
    for (int t = 0; t < NT; ++t) acc[t] = (fx4){0.f, 0.f, 0.f, 0.f};
    int xoff[NT];
    #pragma unroll
    for (int t = 0; t < NT; ++t) xoff[t] = ((wv*NT + t)*16 + lm) * (RSTR*2);

    const float* feat = feat_all + (size_t)b * C * H * W;
    const unsigned short* Wb = Wswz + ((size_t)lb*KT)*512 + lane*8;

    for (int c0 = 0; c0 < C; c0 += CC) {
        // ---- stage CC channels: rt-fastest => 16 consecutive lanes write
        // 16 contiguous 8B chunks (conflict-free ds_write). 4x4 transpose.
        for (int it = tid; it < CC*NCT*NROWT; it += 256) {
            int rt = it % NROWT; int t2 = it / NROWT;
            int ct = t2 % NCT;   int ch = t2 / NCT;
            const float* src = feat + (size_t)(c0 + ch)*H*W;
            int col0 = ct*4, r0 = rt*4;
            int x0 = col0 - P;
            float v[4][4];
            #pragma unroll
            for (int rr = 0; rr < 4; ++rr) {
                int ky = r0 + rr;
                int y = y0 + ky - P;
                bool yok = (ky < KH) && (y >= 0) && (y < H);
                if (yok && x0 >= 0 && x0 + 3 < W) {
                    const float4 f = *reinterpret_cast<const float4*>(src + (size_t)y*W + x0);
                    v[rr][0] = f.x; v[rr][1] = f.y; v[rr][2] = f.z; v[rr][3] = f.w;
                } else {
                    #pragma unroll
                    for (int j = 0; j < 4; ++j) {
                        int x = x0 + j;
                        v[rr][j] = (yok && x >= 0 && x < W) ? src[(size_t)y*W + x] : 0.f;
                    }
                }
            }
            #pragma unroll
            for (int j = 0; j < 4; ++j) {
                unsigned int lo = bf16rne(v[0][j]) | (bf16rne(v[1][j]) << 16);
                unsigned int hi = bf16rne(v[2][j]) | (bf16rne(v[3][j]) << 16);
                *reinterpret_cast<uint2*>(smem + ch*CHSTRB + (col0 + j)*(RSTR*2) + r0*2)
                    = make_uint2(lo, hi);
            }
        }
        __syncthreads();
        // ---- MFMA K-loop over this chunk ----
        const unsigned short* Wk = Wb + (size_t)(c0*KSC)*512;
        #pragma unroll 4
        for (int kk = 0; kk < NKK; ++kk) {
            unsigned int tb = tbl[kk*4 + g];
            bfx8 af = *reinterpret_cast<const bfx8*>(Wk + (size_t)kk*512);
            #pragma unroll
            for (int t = 0; t < NT; ++t) {
                bfx8 bq = *reinterpret_cast<const bfx8*>(smem + tb + xoff[t]);
                acc[t] = __builtin_amdgcn_mfma_f32_16x16x32_bf16(af, bq, acc[t], 0, 0, 0);
            }
        }
        __syncthreads();
    }
    // ---- epilogue: D row=(lane>>4)*4+r = filter m (sc*N+n), col=lane&15 ----
    #pragma unroll
    for (int t = 0; t < NT; ++t) {
        int x = (wv*NT + t)*16 + lm;
        #pragma unroll
        for (int r = 0; r < 4; ++r) {
            int m  = g*4 + r;
            int sc = m / N;
            int n  = m - sc*N;
            if (sc < 3) {
                size_t oi = ((size_t)((b*N + n)*planes + sc)*H + y0)*W + x;
                dst[oi] = acc[t][r];
            }
        }
    }
}

// 64x64 -> 128x128 bilinear upsample of m4 sims into out slots s=3..5.
__global__ void k_upsample(const float* __restrict__ sim4, float* __restrict__ out,
                           int B, int N) {
    int idx = blockIdx.x * blockDim.x + threadIdx.x;
    int total = B * N * 3 * 128 * 128;
    if (idx >= total) return;
    int x = idx % 128; int r = idx / 128;
    int y = r % 128; r /= 128;
    int sc = r % 3; r /= 3;
    int n = r % N; int b = r / N;
    int y0, y1, x0, x1; float wy, wx;
    bl_w(y, 128, 64, y0, y1, wy);
    bl_w(x, 128, 64, x0, x1, wx);
    const float* s = sim4 + (size_t)((b*N + n) * 3 + sc) * 64 * 64;
    float f00 = s[y0*64 + x0], f10 = s[y1*64 + x0];
    float f01 = s[y0*64 + x1], f11 = s[y1*64 + x1];
    out[((size_t)((b*N + n) * 6 + 3 + sc) * 128 + y) * 128 + x] =
        (f00 * (1.f - wy) + f10 * wy) * (1.f - wx)
      + (f01 * (1.f - wy) + f11 * wy) * wx;
}

extern "C" void kernel_launch(void* const* d_in, const int* in_sizes, int n_in,
                              void* d_out, int out_size, void* d_ws, size_t ws_size,
                              hipStream_t stream) {
    const float* map3 = (const float*)d_in[0];
    const float* map4 = (const float*)d_in[1];
    const int*   tlbr = (const int*)d_in[2];
    const int*   p_imgh = (const int*)d_in[3];
    const int*   p_imgw = (const int*)d_in[4];
    float* out = (float*)d_out;

    const int C3 = 512, H3 = 128, C4 = 1024, H4 = 64;
    int B = in_sizes[0] / (C3 * H3 * H3);
    int N = in_sizes[2] / (B * 4);
    int ms = 2 + 4 * N + 6;
    const int MH3 = 24, MH4 = 16;

    char* wsp = (char*)d_ws;
    int* meta = (int*)wsp;
    size_t off = 4096;
    float* sim4 = (float*)(wsp + off);
    off += (size_t)B * N * 3 * H4 * H4 * 4;
    float* patches = (float*)(wsp + off);
    size_t pb3 = (size_t)B * N * C3 * MH3 * MH3 * 4;
    size_t pb4 = (size_t)B * N * C4 * MH4 * MH4 * 4;
    off += (pb3 > pb4 ? pb3 : pb4);
    unsigned short* Wbuf = (unsigned short*)(wsp + off);
    size_t wavail = (ws_size > off) ? (ws_size - off) : 0;
    size_t wpb3 = (size_t)16 * C3 * 24 * 24 * 2;   // 9.44 MB per batch
    size_t wpb4 = (size_t)16 * C4 * 16 * 16 * 2;   // 8.39 MB per batch
    int cb3 = (int)(wavail / wpb3); if (cb3 > B) cb3 = B; if (cb3 < 1) cb3 = 1;
    int cb4 = (int)(wavail / wpb4); if (cb4 > B) cb4 = B; if (cb4 < 1) cb4 = 1;

    k_meta<<<1, 1, 0, stream>>>(tlbr, p_imgh, p_imgw, B, N, ms, meta);

    { // ---- level 0 (m3) ----
        long long tot = (long long)B * N * C3 * MH3 * MH3;
        k_patches<<<(int)((tot + 255) / 256), 256, 0, stream>>>(
            map3, C3, H3, H3, patches, MH3, MH3, B, N, 0, ms, meta);
        for (int b0 = 0; b0 < B; b0 += cb3) {
            int cb = (cb3 < B - b0) ? cb3 : (B - b0);
            long long pr = (long long)cb * (C3 * 24 * 24 / 32) * 256;
            k_filters<512,24,24,24,24><<<(int)((pr + 255) / 256), 256, 0, stream>>>(
                patches, meta, Wbuf, b0, cb, N, 0, ms);
            dim3 grid(H3, cb);
            k_mfconv<512,24,24,128,128,4,2,152,12><<<grid, 256, 0, stream>>>(
                map3, Wbuf, out, b0, N, 6);
        }
    }
    { // ---- level 1 (m4) ----
        long long tot = (long long)B * N * C4 * MH4 * MH4;
        k_patches<<<(int)((tot + 255) / 256), 256, 0, stream>>>(
            map4, C4, H4, H4, patches, MH4, MH4, B, N, 1, ms, meta);
        for (int b0 = 0; b0 < B; b0 += cb4) {
            int cb = (cb4 < B - b0) ? cb4 : (B - b0);
            long long pr = (long long)cb * (C4 * 16 * 16 / 32) * 256;
            k_filters<1024,16,16,16,16><<<(int)((pr + 255) / 256), 256, 0, stream>>>(
                patches, meta, Wbuf, b0, cb, N, 1, ms);
            dim3 grid(H4, cb);
            k_mfconv<1024,16,16,64,64,8,1,80,8><<<grid, 256, 0, stream>>>(
                map4, Wbuf, sim4, b0, N, 3);
        }
        int tot2 = B * N * 3 * H3 * H3;
        k_upsample<<<(tot2 + 255) / 256, 256, 0, stream>>>(sim4, out, B, N);
    }
}

// Round 4
// 1791.717 us; speedup vs baseline: 1.7501x; 1.7501x over previous
//
#include <hip/hip_runtime.h>
#include <math.h>

typedef float  fx4  __attribute__((ext_vector_type(4)));
typedef short  bfx8 __attribute__((ext_vector_type(8)));

// Bilinear weights exactly mirroring the reference resize_bilinear.
__device__ __forceinline__ void bl_w(int o, int O, int I, int& i0, int& i1, float& w) {
    float r = (float)((double)I / (double)O);
    float f = (o + 0.5f) * r - 0.5f;
    f = fminf(fmaxf(f, 0.0f), (float)(I - 1));
    int a = (int)floorf(f);
    i0 = a;
    i1 = min(a + 1, I - 1);
    w = f - (float)a;
}

__device__ __forceinline__ unsigned int bf16rne(float f) {
    unsigned int x = __builtin_bit_cast(unsigned int, f);
    return ((x + 0x7fffu + ((x >> 16) & 1u)) >> 16) & 0xffffu;
}

// Meta: per (b,lvl): [0]=mh [1]=mw ; [2+4n..]=t,l,ch,cw ; [2+4N+2s..]=fh,fw (s=1.0,0.9,1.1)
__global__ void k_meta(const int* __restrict__ tlbr, const int* __restrict__ p_imgh,
                       const int* __restrict__ p_imgw, int B, int N, int ms,
                       int* __restrict__ meta) {
    if (blockIdx.x != 0 || threadIdx.x != 0) return;
    const int HFs[2] = {128, 64};
    const double SC[2] = {0.9, 1.1};
    int img_h = *p_imgh, img_w = *p_imgw;
    for (int b = 0; b < B; ++b)
      for (int lvl = 0; lvl < 2; ++lvl) {
        int HF = HFs[lvl], WF = HFs[lvl];
        double sh = (double)HF / (double)img_h;
        double sw = (double)WF / (double)img_w;
        int* m = meta + (b*2 + lvl)*ms;
        int mh = 0, mw = 0;
        for (int n = 0; n < N; ++n) {
            const int* bx = tlbr + ((size_t)(b*N) + n)*4;
            int t  = max((int)floor((double)bx[0]*sh), 0);
            int l  = max((int)floor((double)bx[1]*sw), 0);
            int bb = min((int)ceil((double)bx[2]*sh) + 1, HF);
            int rr = min((int)ceil((double)bx[3]*sw) + 1, WF);
            int chh = bb - t, cww = rr - l;
            m[2+4*n+0] = t; m[2+4*n+1] = l; m[2+4*n+2] = chh; m[2+4*n+3] = cww;
            mh = max(mh, chh); mw = max(mw, cww);
        }
        m[0] = mh; m[1] = mw;
        int fo = 2 + 4*N;
        m[fo+0] = mh; m[fo+1] = mw;
        for (int s = 0; s < 2; ++s) {
            int hs  = (int)ceil((double)mh * SC[s]); if (hs  <= 1) hs  = mh;
            int wsv = (int)ceil((double)mw * SC[s]); if (wsv <= 1) wsv = mw;
            m[fo+2+2*s] = hs; m[fo+2+2*s+1] = wsv;
        }
      }
}

// Fused crop-resize + filter-resize (two-stage bilinear inlined, bit-identical
// to the previous k_patches->k_filters pipeline), output in MFMA A-frag
// swizzled order: u32 pair index = (((lb*KT + kt)*4 + g)*16 + m)*4 + jj/2,
// k = kt*32 + g*8 + jj, k = c*KH*KW + kx*KH + ky (ky innermost).
template<int C, int KH, int KW>
__global__ void k_filters(const float* __restrict__ feat_all, const int* __restrict__ meta,
                          unsigned short* __restrict__ Wswz, int b0, int chunkB,
                          int N, int lvl, int ms, int HF, int WF) {
    constexpr int KHW = KH*KW;
    constexpr int KT  = C*KHW/32;
    long long idx = (long long)blockIdx.x*256 + threadIdx.x;
    long long total = (long long)chunkB * KT * 256;   // u32 pairs
    if (idx >= total) return;
    int jj = ((int)(idx & 3)) * 2;
    int m  = (int)((idx >> 2) & 15);
    int g  = (int)((idx >> 6) & 3);
    long long rest = idx >> 8;
    int kt = (int)(rest % KT);
    int lb = (int)(rest / KT);
    unsigned int outv = 0;
    int sc = m / N, n = m - sc*N;
    if (sc < 3) {
        int b = b0 + lb;
        const int* mt = meta + (b*2 + lvl)*ms;
        int mh = mt[0], mw = mt[1];
        int t = mt[2+4*n], l = mt[3+4*n], chh = mt[4+4*n], cww = mt[5+4*n];
        int fo = 2 + 4*N;
        int fh = mt[fo + 2*sc], fw = mt[fo + 2*sc + 1];
        int offy = KH/2 - fh/2, offx = KW/2 - fw/2;
        int k = kt*32 + g*8 + jj;
        int c = k / KHW; int rem = k - c*KHW;
        int kx = rem / KH; int ky = rem - kx*KH;
        int fx = kx - offx;
        if (fx >= 0 && fx < fw) {
            const float* src = feat_all + ((size_t)b*C + c)*HF*WF;
            int px0, px1; float wx;
            bl_w(fx, fw, mw, px0, px1, wx);
            int ax0, ax1; float awx; bl_w(px0, mw, cww, ax0, ax1, awx);
            int bx0, bx1; float bwx; bl_w(px1, mw, cww, bx0, bx1, bwx);
            #pragma unroll
            for (int q = 0; q < 2; ++q) {
                int fy = ky + q - offy;
                if (fy >= 0 && fy < fh) {
                    int py0, py1; float wy;
                    bl_w(fy, fh, mh, py0, py1, wy);
                    float pv[2][2];
                    #pragma unroll
                    for (int pi = 0; pi < 2; ++pi) {
                        int py = pi ? py1 : py0;
                        int cy0, cy1; float cwy;
                        bl_w(py, mh, chh, cy0, cy1, cwy);
                        const float* r0 = src + (size_t)(t + cy0)*WF + l;
                        const float* r1 = src + (size_t)(t + cy1)*WF + l;
                        pv[pi][0] = (r0[ax0]*(1.f-cwy) + r1[ax0]*cwy)*(1.f-awx)
                                  + (r0[ax1]*(1.f-cwy) + r1[ax1]*cwy)*awx;
                        pv[pi][1] = (r0[bx0]*(1.f-cwy) + r1[bx0]*cwy)*(1.f-bwx)
                                  + (r0[bx1]*(1.f-cwy) + r1[bx1]*cwy)*bwx;
                    }
                    float v = (pv[0][0]*(1.f-wy) + pv[1][0]*wy)*(1.f-wx)
                            + (pv[0][1]*(1.f-wy) + pv[1][1]*wy)*wx;
                    outv |= bf16rne(v) << (16*q);
                }
            }
        }
    }
    ((unsigned int*)Wswz)[idx] = outv;
}

// MFMA implicit-GEMM xcorr, split-K. Block = one output row, 4 waves, NT
// 16-pixel tiles/wave, channels [ksp*KS, ksp*KS+KS). Feature tile staged
// column-major bf16 (48B columns = odd x 16B: conflict-limited ds_read_b128),
// partial sums to part[ksp].
template<int C, int KS, int KH, int KW, int H, int W, int CC, int NT, int NCOLP, int P>
__global__ __launch_bounds__(256, 8) void k_mfconv(
        const float* __restrict__ feat_all, const unsigned short* __restrict__ Wswz,
        float* __restrict__ part, int b0, int Btot, int N) {
    constexpr int KHW    = KH*KW;
    constexpr int KSC    = KHW/32;          // K-steps per channel
    constexpr int NKK    = CC*KSC;          // K-steps per staged chunk
    constexpr int RSTR   = 24;              // LDS rows per column (48B)
    constexpr int CHSTRB = NCOLP*RSTR*2;    // LDS bytes per channel
    constexpr int NCT    = NCOLP/4;
    constexpr int NROWT  = KH/4;
    constexpr int KT     = C*KSC;
    __shared__ __align__(16) unsigned char smem[CC*CHSTRB];

    const int y0  = blockIdx.x;
    const int lb  = blockIdx.y;
    const int ksp = blockIdx.z;
    const int b   = b0 + lb;
    const int tid = threadIdx.x;
    const int lane = tid & 63;
    const int wv   = tid >> 6;
    const int g    = lane >> 4;
    const int lm   = lane & 15;

    fx4 acc[NT];
    #pragma unroll
    for (int t = 0; t < NT; ++t) acc[t] = (fx4){0.f, 0.f, 0.f, 0.f};
    int xoff[NT];
    #pragma unroll
    for (int t = 0; t < NT; ++t) xoff[t] = ((wv*NT + t)*16 + lm) * (RSTR*2);

    const float* feat = feat_all + (size_t)b * C * H * W;
    const unsigned short* Wb = Wswz + ((size_t)lb*KT)*512 + lane*8;

    const int cbase = ksp * KS;
    for (int c0 = cbase; c0 < cbase + KS; c0 += CC) {
        // ---- stage CC channels: rt-fastest => contiguous ds_write, 4x4 transpose
        for (int it = tid; it < CC*NCT*NROWT; it += 256) {
            int rt = it % NROWT; int t2 = it / NROWT;
            int ct = t2 % NCT;   int ch = t2 / NCT;
            const float* src = feat + (size_t)(c0 + ch)*H*W;
            int col0 = ct*4, r0 = rt*4;
            int x0 = col0 - P;
            float v[4][4];
            #pragma unroll
            for (int rr = 0; rr < 4; ++rr) {
                int ky = r0 + rr;
                int y = y0 + ky - P;
                bool yok = (y >= 0) && (y < H);
                if (yok && x0 >= 0 && x0 + 3 < W) {
                    const float4 f = *reinterpret_cast<const float4*>(src + (size_t)y*W + x0);
                    v[rr][0] = f.x; v[rr][1] = f.y; v[rr][2] = f.z; v[rr][3] = f.w;
                } else {
                    #pragma unroll
                    for (int j = 0; j < 4; ++j) {
                        int x = x0 + j;
                        v[rr][j] = (yok && x >= 0 && x < W) ? src[(size_t)y*W + x] : 0.f;
                    }
                }
            }
            #pragma unroll
            for (int j = 0; j < 4; ++j) {
                unsigned int lo = bf16rne(v[0][j]) | (bf16rne(v[1][j]) << 16);
                unsigned int hi = bf16rne(v[2][j]) | (bf16rne(v[3][j]) << 16);
                *reinterpret_cast<uint2*>(smem + ch*CHSTRB + (col0 + j)*(RSTR*2) + r0*2)
                    = make_uint2(lo, hi);
            }
        }
        __syncthreads();
        // ---- MFMA K-loop; B-address tracked incrementally on VALU ----
        const unsigned short* Wk = Wb + (size_t)(c0*KSC)*512;
        int kx  = (g*8) / KH;
        int ky  = (g*8) % KH;
        int cof = 0;
        #pragma unroll 4
        for (int kk = 0; kk < NKK; ++kk) {
            unsigned int tb = (unsigned int)(cof*CHSTRB + (kx*RSTR + ky)*2);
            bfx8 af = *reinterpret_cast<const bfx8*>(Wk + (size_t)kk*512);
            #pragma unroll
            for (int t = 0; t < NT; ++t) {
                bfx8 bq = *reinterpret_cast<const bfx8*>(smem + tb + xoff[t]);
                acc[t] = __builtin_amdgcn_mfma_f32_16x16x32_bf16(af, bq, acc[t], 0, 0, 0);
            }
            ky += 32 % KH;
            kx += 32 / KH;
            if (ky >= KH) { ky -= KH; kx += 1; }
            if (kx >= KW) { kx -= KW; cof += 1; }
        }
        __syncthreads();
    }
    // ---- epilogue: D row = g*4+r = filter m (sc*N+n), col = lane&15 ----
    #pragma unroll
    for (int t = 0; t < NT; ++t) {
        int x = (wv*NT + t)*16 + lm;
        #pragma unroll
        for (int r = 0; r < 4; ++r) {
            int m  = g*4 + r;
            int sc = m / N;
            int n  = m - sc*N;
            if (sc < 3) {
                size_t oi = ((((size_t)ksp*Btot + b)*N + n)*3 + sc)*((size_t)H*W)
                          + (size_t)y0*W + x;
                part[oi] = acc[t][r];
            }
        }
    }
}

// Sum m3 split-K partials -> out planes 0..2.
__global__ void k_reduce3(const float* __restrict__ part, float* __restrict__ out,
                          int B, int N, int nks) {
    int idx = blockIdx.x*256 + threadIdx.x;
    int tot = B*N*3*128*128;
    if (idx >= tot) return;
    int px = idx & 16383;
    int r = idx >> 14;
    int sc = r % 3; r /= 3;
    int n = r % N; int b = r / N;
    size_t stride = (size_t)B*N*3*16384;
    const float* p = part + ((size_t)(b*N + n)*3 + sc)*16384 + px;
    float s = 0.f;
    for (int ks = 0; ks < nks; ++ks) s += p[(size_t)ks*stride];
    out[(((size_t)(b*N + n)*6 + sc) << 14) + px] = s;
}

// Sum m4 split-K partials + 64->128 bilinear upsample -> out planes 3..5.
__global__ void k_upsample_sum(const float* __restrict__ part, float* __restrict__ out,
                               int B, int N, int nks) {
    int idx = blockIdx.x*256 + threadIdx.x;
    int tot = B*N*3*128*128;
    if (idx >= tot) return;
    int x = idx & 127; int r = idx >> 7;
    int y = r & 127; r >>= 7;
    int sc = r % 3; r /= 3;
    int n = r % N; int b = r / N;
    int y0, y1, x0, x1; float wy, wx;
    bl_w(y, 128, 64, y0, y1, wy);
    bl_w(x, 128, 64, x0, x1, wx);
    size_t stride = (size_t)B*N*3*4096;
    const float* p = part + ((size_t)(b*N + n)*3 + sc)*4096;
    float f00 = 0.f, f10 = 0.f, f01 = 0.f, f11 = 0.f;
    for (int ks = 0; ks < nks; ++ks) {
        const float* q = p + (size_t)ks*stride;
        f00 += q[y0*64 + x0]; f10 += q[y1*64 + x0];
        f01 += q[y0*64 + x1]; f11 += q[y1*64 + x1];
    }
    out[((size_t)((b*N + n)*6 + 3 + sc)*128 + y)*128 + x] =
        (f00*(1.f-wy) + f10*wy)*(1.f-wx) + (f01*(1.f-wy) + f11*wy)*wx;
}

extern "C" void kernel_launch(void* const* d_in, const int* in_sizes, int n_in,
                              void* d_out, int out_size, void* d_ws, size_t ws_size,
                              hipStream_t stream) {
    const float* map3 = (const float*)d_in[0];
    const float* map4 = (const float*)d_in[1];
    const int*   tlbr = (const int*)d_in[2];
    const int*   p_imgh = (const int*)d_in[3];
    const int*   p_imgw = (const int*)d_in[4];
    float* out = (float*)d_out;

    const int C3 = 512, H3 = 128, C4 = 1024, H4 = 64;
    int B = in_sizes[0] / (C3 * H3 * H3);
    int N = in_sizes[2] / (B * 4);
    int ms = 2 + 4 * N + 6;
    const int NKS3 = 4, NKS4 = 8;   // split-K factors (KS=128 channels/block)

    // Workspace: meta (4KB) | part (split-K partials, shared m3/m4) | Wbuf
    char* wsp = (char*)d_ws;
    int* meta = (int*)wsp;
    size_t off = 4096;
    float* part = (float*)(wsp + off);
    size_t part_bytes = (size_t)NKS3 * B * N * 3 * H3 * H3 * 4;  // >= m4 partials
    off += part_bytes;
    unsigned short* Wbuf = (unsigned short*)(wsp + off);
    size_t wavail = (ws_size > off) ? (ws_size - off) : 0;
    size_t wpb = (size_t)(C3 * 24 * 24 / 32) * 1024;   // 9.44MB/batch (>= m4's 8.39MB)
    int cb = (int)(wavail / wpb); if (cb > B) cb = B; if (cb < 1) cb = 1;

    k_meta<<<1, 1, 0, stream>>>(tlbr, p_imgh, p_imgw, B, N, ms, meta);

    { // ---- level 0 (m3): filters -> split-K conv -> reduce ----
        for (int b0 = 0; b0 < B; b0 += cb) {
            int cbn = (cb < B - b0) ? cb : (B - b0);
            long long pr = (long long)cbn * (C3 * 24 * 24 / 32) * 256;
            k_filters<512,24,24><<<(int)((pr + 255) / 256), 256, 0, stream>>>(
                map3, meta, Wbuf, b0, cbn, N, 0, ms, H3, H3);
            dim3 grid(H3, cbn, NKS3);
            k_mfconv<512,128,24,24,128,128,2,2,152,12><<<grid, 256, 0, stream>>>(
                map3, Wbuf, part, b0, B, N);
        }
        int tot = B * N * 3 * H3 * H3;
        k_reduce3<<<(tot + 255) / 256, 256, 0, stream>>>(part, out, B, N, NKS3);
    }
    { // ---- level 1 (m4): filters -> split-K conv -> fused reduce+upsample ----
        for (int b0 = 0; b0 < B; b0 += cb) {
            int cbn = (cb < B - b0) ? cb : (B - b0);
            long long pr = (long long)cbn * (C4 * 16 * 16 / 32) * 256;
            k_filters<1024,16,16><<<(int)((pr + 255) / 256), 256, 0, stream>>>(
                map4, meta, Wbuf, b0, cbn, N, 1, ms, H4, H4);
            dim3 grid(H4, cbn, NKS4);
            k_mfconv<1024,128,16,16,64,64,4,1,80,8><<<grid, 256, 0, stream>>>(
                map4, Wbuf, part, b0, B, N);
        }
        int tot = B * N * 3 * H3 * H3;
        k_upsample_sum<<<(tot + 255) / 256, 256, 0, stream>>>(part, out, B, N, NKS4);
    }
}

// Round 5
// 1163.567 us; speedup vs baseline: 2.6948x; 1.5398x over previous
//
#include <hip/hip_runtime.h>
#include <math.h>

typedef float  fx4  __attribute__((ext_vector_type(4)));
typedef short  bfx8 __attribute__((ext_vector_type(8)));

// Bilinear weights exactly mirroring the reference resize_bilinear.
__device__ __forceinline__ void bl_w(int o, int O, int I, int& i0, int& i1, float& w) {
    float r = (float)((double)I / (double)O);
    float f = (o + 0.5f) * r - 0.5f;
    f = fminf(fmaxf(f, 0.0f), (float)(I - 1));
    int a = (int)floorf(f);
    i0 = a;
    i1 = min(a + 1, I - 1);
    w = f - (float)a;
}

__device__ __forceinline__ unsigned int bf16rne(float f) {
    unsigned int x = __builtin_bit_cast(unsigned int, f);
    return ((x + 0x7fffu + ((x >> 16) & 1u)) >> 16) & 0xffffu;
}

// Meta: per (b,lvl): [0]=mh [1]=mw ; [2+4n..]=t,l,ch,cw ; [2+4N+2s..]=fh,fw (s=1.0,0.9,1.1)
__global__ void k_meta(const int* __restrict__ tlbr, const int* __restrict__ p_imgh,
                       const int* __restrict__ p_imgw, int B, int N, int ms,
                       int* __restrict__ meta) {
    if (blockIdx.x != 0 || threadIdx.x != 0) return;
    const int HFs[2] = {128, 64};
    const double SC[2] = {0.9, 1.1};
    int img_h = *p_imgh, img_w = *p_imgw;
    for (int b = 0; b < B; ++b)
      for (int lvl = 0; lvl < 2; ++lvl) {
        int HF = HFs[lvl], WF = HFs[lvl];
        double sh = (double)HF / (double)img_h;
        double sw = (double)WF / (double)img_w;
        int* m = meta + (b*2 + lvl)*ms;
        int mh = 0, mw = 0;
        for (int n = 0; n < N; ++n) {
            const int* bx = tlbr + ((size_t)(b*N) + n)*4;
            int t  = max((int)floor((double)bx[0]*sh), 0);
            int l  = max((int)floor((double)bx[1]*sw), 0);
            int bb = min((int)ceil((double)bx[2]*sh) + 1, HF);
            int rr = min((int)ceil((double)bx[3]*sw) + 1, WF);
            int chh = bb - t, cww = rr - l;
            m[2+4*n+0] = t; m[2+4*n+1] = l; m[2+4*n+2] = chh; m[2+4*n+3] = cww;
            mh = max(mh, chh); mw = max(mw, cww);
        }
        m[0] = mh; m[1] = mw;
        int fo = 2 + 4*N;
        m[fo+0] = mh; m[fo+1] = mw;
        for (int s = 0; s < 2; ++s) {
            int hs  = (int)ceil((double)mh * SC[s]); if (hs  <= 1) hs  = mh;
            int wsv = (int)ceil((double)mw * SC[s]); if (wsv <= 1) wsv = mw;
            m[fo+2+2*s] = hs; m[fo+2+2*s+1] = wsv;
        }
      }
}

// Fused crop-resize + filter-resize, output in MFMA A-frag swizzled order.
// K-step s = (cgroup, kx, kyg): lane-group g holds channel c = cg*4+g,
// rows ky = kyg*8 + j. u32 pair idx = (((lb*KT + s)*4 + g)*16 + m)*4 + jj/2.
template<int C, int KH, int KW, int NKYG>
__global__ void k_filters(const float* __restrict__ feat_all, const int* __restrict__ meta,
                          unsigned short* __restrict__ Wswz, int b0, int chunkB,
                          int N, int lvl, int ms, int HF, int WF) {
    constexpr int KT = (C/4)*KW*NKYG;
    long long idx = (long long)blockIdx.x*256 + threadIdx.x;
    long long total = (long long)chunkB * KT * 256;   // u32 pairs
    if (idx >= total) return;
    int jj = ((int)(idx & 3)) * 2;
    int m  = (int)((idx >> 2) & 15);
    int g  = (int)((idx >> 6) & 3);
    long long rest = idx >> 8;
    int s  = (int)(rest % KT);
    int lb = (int)(rest / KT);
    int kyg = s % NKYG; int s2 = s / NKYG;
    int kx  = s2 % KW;
    int cg  = s2 / KW;
    int c   = cg*4 + g;
    int ky  = kyg*8 + jj;
    unsigned int outv = 0;
    int sc = m / N, n = m - sc*N;
    if (sc < 3) {
        int b = b0 + lb;
        const int* mt = meta + (b*2 + lvl)*ms;
        int mh = mt[0], mw = mt[1];
        int t = mt[2+4*n], l = mt[3+4*n], chh = mt[4+4*n], cww = mt[5+4*n];
        int fo = 2 + 4*N;
        int fh = mt[fo + 2*sc], fw = mt[fo + 2*sc + 1];
        int offy = KH/2 - fh/2, offx = KW/2 - fw/2;
        int fx = kx - offx;
        if (fx >= 0 && fx < fw) {
            const float* src = feat_all + ((size_t)b*C + c)*HF*WF;
            int px0, px1; float wx;
            bl_w(fx, fw, mw, px0, px1, wx);
            int ax0, ax1; float awx; bl_w(px0, mw, cww, ax0, ax1, awx);
            int bx0, bx1; float bwx; bl_w(px1, mw, cww, bx0, bx1, bwx);
            #pragma unroll
            for (int q = 0; q < 2; ++q) {
                int fy = ky + q - offy;
                if (fy >= 0 && fy < fh) {
                    int py0, py1; float wy;
                    bl_w(fy, fh, mh, py0, py1, wy);
                    float pv[2][2];
                    #pragma unroll
                    for (int pi = 0; pi < 2; ++pi) {
                        int py = pi ? py1 : py0;
                        int cy0, cy1; float cwy;
                        bl_w(py, mh, chh, cy0, cy1, cwy);
                        const float* r0 = src + (size_t)(t + cy0)*WF + l;
                        const float* r1 = src + (size_t)(t + cy1)*WF + l;
                        pv[pi][0] = (r0[ax0]*(1.f-cwy) + r1[ax0]*cwy)*(1.f-awx)
                                  + (r0[ax1]*(1.f-cwy) + r1[ax1]*cwy)*awx;
                        pv[pi][1] = (r0[bx0]*(1.f-cwy) + r1[bx0]*cwy)*(1.f-bwx)
                                  + (r0[bx1]*(1.f-cwy) + r1[bx1]*cwy)*bwx;
                    }
                    float v = (pv[0][0]*(1.f-wy) + pv[1][0]*wy)*(1.f-wx)
                            + (pv[0][1]*(1.f-wy) + pv[1][1]*wy)*wx;
                    outv |= bf16rne(v) << (16*q);
                }
            }
        }
    }
    ((unsigned int*)Wswz)[idx] = outv;
}

// MFMA implicit-GEMM xcorr, split-K, multi-row. Block = 64 output px (4
// waves x 1 16-px tile) x 4 output rows {y0,y0+8,y0+16,y0+24}. LDS: 4
// channels staged column-major bf16, RSTR rows/col (odd x 16B: conflict-free
// ds_read_b128). Per kx: NKYG A-frags + (NKYG+3) B-frags feed 4*NKYG MFMAs
// (frag[kyg+dy] reuse); A-frags reused across 4 dy from registers.
template<int C, int KS, int KH, int KW, int H, int W, int NKYG, int RSTR, int NCOL, int P>
__global__ __launch_bounds__(256, 4) void k_mfconv(
        const float* __restrict__ feat_all, const unsigned short* __restrict__ Wswz,
        float* __restrict__ part, int b0, int Btot, int N, int nks) {
    constexpr int NDY   = 4;
    constexpr int CHSTR = NCOL*RSTR;          // u16 elems per channel
    constexpr int NROWS = KH + (NDY-1)*8;     // staged rows per column
    constexpr int NRT   = NROWS/4;
    constexpr int NCT   = NCOL/4;
    constexpr int KT    = (C/4)*KW*NKYG;
    constexpr int NFR   = NKYG + NDY - 1;     // B-frags per kx
    __shared__ __align__(16) unsigned short smem[4*CHSTR];

    const int xb  = blockIdx.x;
    const int yb  = blockIdx.y;
    const int zz  = blockIdx.z;
    const int ksp = zz % nks;
    const int lb  = zz / nks;
    const int b   = b0 + lb;
    const int y0  = (yb >> 3)*32 + (yb & 7);
    const int tid = threadIdx.x;
    const int lane = tid & 63;
    const int wv   = tid >> 6;
    const int g    = lane >> 4;
    const int lm   = lane & 15;

    fx4 acc[NDY];
    #pragma unroll
    for (int t = 0; t < NDY; ++t) acc[t] = (fx4){0.f, 0.f, 0.f, 0.f};

    const float* feat = feat_all + (size_t)b * C * H * W;
    const unsigned short* Wlane = Wswz + ((size_t)lb*KT)*512 + lane*8;
    const int bcol = g*CHSTR + (wv*16 + lm)*RSTR;   // per-lane B base (elems)

    const int cg0 = ksp * (KS/4);
    for (int cgl = 0; cgl < KS/4; ++cgl) {
        const int c0 = (cg0 + cgl)*4;
        // ---- stage 4 channels: 4x4 transpose, rt-fastest contiguous writes
        for (int it = tid; it < 4*NCT*NRT; it += 256) {
            int rt = it % NRT; int t2 = it / NRT;
            int ct = t2 % NCT; int ch = t2 / NCT;
            const float* src = feat + (size_t)(c0 + ch)*H*W;
            int col0 = ct*4, r0 = rt*4;
            int x0 = xb*64 + col0 - P;
            float v[4][4];
            #pragma unroll
            for (int rr = 0; rr < 4; ++rr) {
                int y = y0 + r0 + rr - P;
                bool yok = (y >= 0) && (y < H);
                if (yok && x0 >= 0 && x0 + 3 < W) {
                    const float4 f = *reinterpret_cast<const float4*>(src + (size_t)y*W + x0);
                    v[rr][0] = f.x; v[rr][1] = f.y; v[rr][2] = f.z; v[rr][3] = f.w;
                } else {
                    #pragma unroll
                    for (int j = 0; j < 4; ++j) {
                        int x = x0 + j;
                        v[rr][j] = (yok && x >= 0 && x < W) ? src[(size_t)y*W + x] : 0.f;
                    }
                }
            }
            #pragma unroll
            for (int j = 0; j < 4; ++j) {
                unsigned int lo = bf16rne(v[0][j]) | (bf16rne(v[1][j]) << 16);
                unsigned int hi = bf16rne(v[2][j]) | (bf16rne(v[3][j]) << 16);
                *reinterpret_cast<uint2*>(smem + ch*CHSTR + (col0 + j)*RSTR + r0)
                    = make_uint2(lo, hi);
            }
        }
        __syncthreads();
        // ---- per kx: NKYG A-loads, NFR B-reads, 4*NKYG MFMAs ----
        const unsigned short* Wc = Wlane + (size_t)((cg0 + cgl)*KW*NKYG)*512;
        for (int kx = 0; kx < KW; ++kx) {
            bfx8 af[NKYG];
            #pragma unroll
            for (int kyg = 0; kyg < NKYG; ++kyg)
                af[kyg] = *reinterpret_cast<const bfx8*>(Wc + (size_t)(kx*NKYG + kyg)*512);
            const unsigned short* bp = smem + bcol + kx*RSTR;
            bfx8 fr[NFR];
            #pragma unroll
            for (int rg = 0; rg < NFR; ++rg)
                fr[rg] = *reinterpret_cast<const bfx8*>(bp + rg*8);
            #pragma unroll
            for (int dy = 0; dy < NDY; ++dy)
                #pragma unroll
                for (int kyg = 0; kyg < NKYG; ++kyg)
                    acc[dy] = __builtin_amdgcn_mfma_f32_16x16x32_bf16(
                        af[kyg], fr[kyg + dy], acc[dy], 0, 0, 0);
        }
        __syncthreads();
    }
    // ---- epilogue: D row = g*4+r = filter m (sc*N+n), col = lane&15 ----
    const int x = xb*64 + wv*16 + lm;
    #pragma unroll
    for (int dy = 0; dy < NDY; ++dy) {
        int y = y0 + dy*8;
        #pragma unroll
        for (int r = 0; r < 4; ++r) {
            int m  = g*4 + r;
            int sc = m / N;
            int n  = m - sc*N;
            if (sc < 3) {
                size_t oi = ((((size_t)ksp*Btot + b)*N + n)*3 + sc)*((size_t)H*W)
                          + (size_t)y*W + x;
                part[oi] = acc[dy][r];
            }
        }
    }
}

// Sum m3 split-K partials -> out planes 0..2.
__global__ void k_reduce3(const float* __restrict__ part, float* __restrict__ out,
                          int B, int N, int nks) {
    int idx = blockIdx.x*256 + threadIdx.x;
    int tot = B*N*3*128*128;
    if (idx >= tot) return;
    int px = idx & 16383;
    int r = idx >> 14;
    int sc = r % 3; r /= 3;
    int n = r % N; int b = r / N;
    size_t stride = (size_t)B*N*3*16384;
    const float* p = part + ((size_t)(b*N + n)*3 + sc)*16384 + px;
    float s = 0.f;
    for (int ks = 0; ks < nks; ++ks) s += p[(size_t)ks*stride];
    out[(((size_t)(b*N + n)*6 + sc) << 14) + px] = s;
}

// Sum m4 split-K partials + 64->128 bilinear upsample -> out planes 3..5.
__global__ void k_upsample_sum(const float* __restrict__ part, float* __restrict__ out,
                               int B, int N, int nks) {
    int idx = blockIdx.x*256 + threadIdx.x;
    int tot = B*N*3*128*128;
    if (idx >= tot) return;
    int x = idx & 127; int r = idx >> 7;
    int y = r & 127; r >>= 7;
    int sc = r % 3; r /= 3;
    int n = r % N; int b = r / N;
    int y0, y1, x0, x1; float wy, wx;
    bl_w(y, 128, 64, y0, y1, wy);
    bl_w(x, 128, 64, x0, x1, wx);
    size_t stride = (size_t)B*N*3*4096;
    const float* p = part + ((size_t)(b*N + n)*3 + sc)*4096;
    float f00 = 0.f, f10 = 0.f, f01 = 0.f, f11 = 0.f;
    for (int ks = 0; ks < nks; ++ks) {
        const float* q = p + (size_t)ks*stride;
        f00 += q[y0*64 + x0]; f10 += q[y1*64 + x0];
        f01 += q[y0*64 + x1]; f11 += q[y1*64 + x1];
    }
    out[((size_t)((b*N + n)*6 + 3 + sc)*128 + y)*128 + x] =
        (f00*(1.f-wy) + f10*wy)*(1.f-wx) + (f01*(1.f-wy) + f11*wy)*wx;
}

extern "C" void kernel_launch(void* const* d_in, const int* in_sizes, int n_in,
                              void* d_out, int out_size, void* d_ws, size_t ws_size,
                              hipStream_t stream) {
    const float* map3 = (const float*)d_in[0];
    const float* map4 = (const float*)d_in[1];
    const int*   tlbr = (const int*)d_in[2];
    const int*   p_imgh = (const int*)d_in[3];
    const int*   p_imgw = (const int*)d_in[4];
    float* out = (float*)d_out;

    const int C3 = 512, H3 = 128, C4 = 1024, H4 = 64;
    int B = in_sizes[0] / (C3 * H3 * H3);
    int N = in_sizes[2] / (B * 4);
    int ms = 2 + 4 * N + 6;
    const int NKS3 = 4, NKS4 = 16;

    // Workspace: meta (4KB) | part (split-K partials, shared m3/m4) | Wbuf
    char* wsp = (char*)d_ws;
    int* meta = (int*)wsp;
    size_t off = 4096;
    float* part = (float*)(wsp + off);
    size_t part_bytes = (size_t)NKS3 * B * N * 3 * H3 * H3 * 4;  // == m4's NKS4 partials
    off += part_bytes;
    unsigned short* Wbuf = (unsigned short*)(wsp + off);
    size_t wavail = (ws_size > off) ? (ws_size - off) : 0;
    size_t wpb = (size_t)(C3/4 * 24 * 3) * 1024;   // 9.44MB/batch (>= m4's 8.39MB)
    int cb = (int)(wavail / wpb); if (cb > B) cb = B; if (cb < 1) cb = 1;

    k_meta<<<1, 1, 0, stream>>>(tlbr, p_imgh, p_imgw, B, N, ms, meta);

    { // ---- level 0 (m3): filters -> split-K multi-row conv -> reduce ----
        for (int b0 = 0; b0 < B; b0 += cb) {
            int cbn = (cb < B - b0) ? cb : (B - b0);
            long long pr = (long long)cbn * (C3/4 * 24 * 3) * 256;
            k_filters<512,24,24,3><<<(int)((pr + 255) / 256), 256, 0, stream>>>(
                map3, meta, Wbuf, b0, cbn, N, 0, ms, H3, H3);
            dim3 grid(2, 32, cbn * NKS3);
            k_mfconv<512,128,24,24,128,128,3,56,88,12><<<grid, 256, 0, stream>>>(
                map3, Wbuf, part, b0, B, N, NKS3);
        }
        int tot = B * N * 3 * H3 * H3;
        k_reduce3<<<(tot + 255) / 256, 256, 0, stream>>>(part, out, B, N, NKS3);
    }
    { // ---- level 1 (m4): filters -> split-K multi-row conv -> reduce+upsample ----
        for (int b0 = 0; b0 < B; b0 += cb) {
            int cbn = (cb < B - b0) ? cb : (B - b0);
            long long pr = (long long)cbn * (C4/4 * 16 * 2) * 256;
            k_filters<1024,16,16,2><<<(int)((pr + 255) / 256), 256, 0, stream>>>(
                map4, meta, Wbuf, b0, cbn, N, 1, ms, H4, H4);
            dim3 grid(1, 16, cbn * NKS4);
            k_mfconv<1024,64,16,16,64,64,2,40,80,8><<<grid, 256, 0, stream>>>(
                map4, Wbuf, part, b0, B, N, NKS4);
        }
        int tot = B * N * 3 * H3 * H3;
        k_upsample_sum<<<(tot + 255) / 256, 256, 0, stream>>>(part, out, B, N, NKS4);
    }
}

// Round 6
// 975.056 us; speedup vs baseline: 3.2158x; 1.1933x over previous
//
#include <hip/hip_runtime.h>
#include <math.h>

typedef float  fx4  __attribute__((ext_vector_type(4)));
typedef short  bfx8 __attribute__((ext_vector_type(8)));

// Bilinear weights exactly mirroring the reference resize_bilinear.
__device__ __forceinline__ void bl_w(int o, int O, int I, int& i0, int& i1, float& w) {
    float r = (float)((double)I / (double)O);
    float f = (o + 0.5f) * r - 0.5f;
    f = fminf(fmaxf(f, 0.0f), (float)(I - 1));
    int a = (int)floorf(f);
    i0 = a;
    i1 = min(a + 1, I - 1);
    w = f - (float)a;
}

__device__ __forceinline__ unsigned int bf16rne(float f) {
    unsigned int x = __builtin_bit_cast(unsigned int, f);
    return ((x + 0x7fffu + ((x >> 16) & 1u)) >> 16) & 0xffffu;
}

// Meta: per (b,lvl): [0]=mh [1]=mw ; [2+4n..]=t,l,ch,cw ; [2+4N+2s..]=fh,fw (s=1.0,0.9,1.1)
__global__ void k_meta(const int* __restrict__ tlbr, const int* __restrict__ p_imgh,
                       const int* __restrict__ p_imgw, int B, int N, int ms,
                       int* __restrict__ meta) {
    if (blockIdx.x != 0 || threadIdx.x != 0) return;
    const int HFs[2] = {128, 64};
    const double SC[2] = {0.9, 1.1};
    int img_h = *p_imgh, img_w = *p_imgw;
    for (int b = 0; b < B; ++b)
      for (int lvl = 0; lvl < 2; ++lvl) {
        int HF = HFs[lvl], WF = HFs[lvl];
        double sh = (double)HF / (double)img_h;
        double sw = (double)WF / (double)img_w;
        int* m = meta + (b*2 + lvl)*ms;
        int mh = 0, mw = 0;
        for (int n = 0; n < N; ++n) {
            const int* bx = tlbr + ((size_t)(b*N) + n)*4;
            int t  = max((int)floor((double)bx[0]*sh), 0);
            int l  = max((int)floor((double)bx[1]*sw), 0);
            int bb = min((int)ceil((double)bx[2]*sh) + 1, HF);
            int rr = min((int)ceil((double)bx[3]*sw) + 1, WF);
            int chh = bb - t, cww = rr - l;
            m[2+4*n+0] = t; m[2+4*n+1] = l; m[2+4*n+2] = chh; m[2+4*n+3] = cww;
            mh = max(mh, chh); mw = max(mw, cww);
        }
        m[0] = mh; m[1] = mw;
        int fo = 2 + 4*N;
        m[fo+0] = mh; m[fo+1] = mw;
        for (int s = 0; s < 2; ++s) {
            int hs  = (int)ceil((double)mh * SC[s]); if (hs  <= 1) hs  = mh;
            int wsv = (int)ceil((double)mw * SC[s]); if (wsv <= 1) wsv = mw;
            m[fo+2+2*s] = hs; m[fo+2+2*s+1] = wsv;
        }
      }
}

// Fused crop-resize + filter-resize, MFMA A-frag swizzled order.
// k-step s = (c, kxg, kyg): lane-group g holds kx = kxg*4+g, j-elems are
// ky = kyg*8+j. u32 pair idx = (((lb*KT + s)*4 + g)*16 + m)*4 + jj/2.
template<int C, int KH, int KW, int NKYG>
__global__ void k_filters(const float* __restrict__ feat_all, const int* __restrict__ meta,
                          unsigned short* __restrict__ Wswz, int b0, int chunkB,
                          int N, int lvl, int ms, int HF, int WF) {
    constexpr int KWG = KW/4;
    constexpr int KT  = C*KWG*NKYG;
    long long idx = (long long)blockIdx.x*256 + threadIdx.x;
    long long total = (long long)chunkB * KT * 256;   // u32 pairs
    if (idx >= total) return;
    int jj = ((int)(idx & 3)) * 2;
    int m  = (int)((idx >> 2) & 15);
    int g  = (int)((idx >> 6) & 3);
    long long rest = idx >> 8;
    int s  = (int)(rest % KT);
    int lb = (int)(rest / KT);
    int kyg = s % NKYG; int s2 = s / NKYG;
    int kxg = s2 % KWG;
    int c   = s2 / KWG;
    int kx  = kxg*4 + g;
    int ky  = kyg*8 + jj;
    unsigned int outv = 0;
    int sc = m / N, n = m - sc*N;
    if (sc < 3) {
        int b = b0 + lb;
        const int* mt = meta + (b*2 + lvl)*ms;
        int mh = mt[0], mw = mt[1];
        int t = mt[2+4*n], l = mt[3+4*n], chh = mt[4+4*n], cww = mt[5+4*n];
        int fo = 2 + 4*N;
        int fh = mt[fo + 2*sc], fw = mt[fo + 2*sc + 1];
        int offy = KH/2 - fh/2, offx = KW/2 - fw/2;
        int fx = kx - offx;
        if (fx >= 0 && fx < fw) {
            const float* src = feat_all + ((size_t)b*C + c)*HF*WF;
            int px0, px1; float wx;
            bl_w(fx, fw, mw, px0, px1, wx);
            int ax0, ax1; float awx; bl_w(px0, mw, cww, ax0, ax1, awx);
            int bx0, bx1; float bwx; bl_w(px1, mw, cww, bx0, bx1, bwx);
            #pragma unroll
            for (int q = 0; q < 2; ++q) {
                int fy = ky + q - offy;
                if (fy >= 0 && fy < fh) {
                    int py0, py1; float wy;
                    bl_w(fy, fh, mh, py0, py1, wy);
                    float pv[2][2];
                    #pragma unroll
                    for (int pi = 0; pi < 2; ++pi) {
                        int py = pi ? py1 : py0;
                        int cy0, cy1; float cwy;
                        bl_w(py, mh, chh, cy0, cy1, cwy);
                        const float* r0 = src + (size_t)(t + cy0)*WF + l;
                        const float* r1 = src + (size_t)(t + cy1)*WF + l;
                        pv[pi][0] = (r0[ax0]*(1.f-cwy) + r1[ax0]*cwy)*(1.f-awx)
                                  + (r0[ax1]*(1.f-cwy) + r1[ax1]*cwy)*awx;
                        pv[pi][1] = (r0[bx0]*(1.f-cwy) + r1[bx0]*cwy)*(1.f-bwx)
                                  + (r0[bx1]*(1.f-cwy) + r1[bx1]*cwy)*bwx;
                    }
                    float v = (pv[0][0]*(1.f-wy) + pv[1][0]*wy)*(1.f-wx)
                            + (pv[0][1]*(1.f-wy) + pv[1][1]*wy)*wx;
                    outv |= bf16rne(v) << (16*q);
                }
            }
        }
    }
    ((unsigned int*)Wswz)[idx] = outv;
}

// MFMA implicit-GEMM xcorr, split-K, 8 output rows/block. Block = 64 px x
// {y0+8*dy, dy<8}. LDS: CC=2 channels column-major bf16, RSTR rows/col
// (odd x 16B -> conflict-free b128 reads AND writes). Per (ch,kxg):
// NKYG A-frags + NFR B-frags feed NKYG*NDY MFMAs (frag[kyg+dy] reuse).
template<int C, int KS, int KH, int KW, int H, int W, int NKYG, int NDY,
         int CC, int RSTR, int NCOL, int P>
__global__ __launch_bounds__(256, 4) void k_mfconv(
        const float* __restrict__ feat_all, const unsigned short* __restrict__ Wswz,
        float* __restrict__ part, int b0, int Btot, int N, int nks) {
    constexpr int KWG   = KW/4;
    constexpr int CHSTR = NCOL*RSTR;          // u16 elems per channel
    constexpr int NROWS = KH + (NDY-1)*8;     // staged rows per column
    constexpr int NRT   = NROWS/8;
    constexpr int NCT   = NCOL/4;
    constexpr int KT    = C*KWG*NKYG;
    constexpr int NFR   = NKYG + NDY - 1;     // B-frags per (ch,kxg)
    __shared__ __align__(16) unsigned short smem[CC*CHSTR];

    const int xb  = blockIdx.x;
    const int yb  = blockIdx.y;
    const int zz  = blockIdx.z;
    const int ksp = zz % nks;
    const int lb  = zz / nks;
    const int b   = b0 + lb;
    const int y0  = (yb >> 3)*(8*NDY) + (yb & 7);
    const int tid = threadIdx.x;
    const int lane = tid & 63;
    const int wv   = tid >> 6;
    const int g    = lane >> 4;
    const int lm   = lane & 15;

    fx4 acc[NDY];
    #pragma unroll
    for (int t = 0; t < NDY; ++t) acc[t] = (fx4){0.f, 0.f, 0.f, 0.f};

    const float* feat = feat_all + (size_t)b * C * H * W;
    const unsigned short* Wlane = Wswz + ((size_t)lb*KT)*512 + lane*8;
    const int bcol0 = (wv*16 + lm + g)*RSTR;   // B base (elems), +4*RSTR per kxg

    for (int cb_ = 0; cb_ < KS; cb_ += CC) {
        const int c0 = ksp*KS + cb_;
        // ---- stage CC channels: 8-row x 4-col transpose tiles, b128 writes
        for (int it = tid; it < CC*NCT*NRT; it += 256) {
            int rt = it % NRT; int t2 = it / NRT;
            int ct = t2 % NCT; int ch = t2 / NCT;
            const float* src = feat + (size_t)(c0 + ch)*H*W;
            int col0 = ct*4, r0 = rt*8;
            int x0 = xb*64 + col0 - P;
            float4 f[8];
            #pragma unroll
            for (int rr = 0; rr < 8; ++rr) {
                int y = y0 + r0 + rr - P;
                bool yok = (y >= 0) && (y < H);
                if (yok && x0 >= 0 && x0 + 3 < W) {
                    f[rr] = *reinterpret_cast<const float4*>(src + (size_t)y*W + x0);
                } else {
                    float t4[4];
                    #pragma unroll
                    for (int j = 0; j < 4; ++j) {
                        int x = x0 + j;
                        t4[j] = (yok && x >= 0 && x < W) ? src[(size_t)y*W + x] : 0.f;
                    }
                    f[rr] = make_float4(t4[0], t4[1], t4[2], t4[3]);
                }
            }
            #pragma unroll
            for (int j = 0; j < 4; ++j) {
                const float* e = (const float*)&f[0];
                uint4 wv4;
                wv4.x = bf16rne(((const float*)&f[0])[j]) | (bf16rne(((const float*)&f[1])[j]) << 16);
                wv4.y = bf16rne(((const float*)&f[2])[j]) | (bf16rne(((const float*)&f[3])[j]) << 16);
                wv4.z = bf16rne(((const float*)&f[4])[j]) | (bf16rne(((const float*)&f[5])[j]) << 16);
                wv4.w = bf16rne(((const float*)&f[6])[j]) | (bf16rne(((const float*)&f[7])[j]) << 16);
                *reinterpret_cast<uint4*>(smem + ch*CHSTR + (col0 + j)*RSTR + r0) = wv4;
                (void)e;
            }
        }
        __syncthreads();
        // ---- MFMA: per (ch,kxg): NKYG A-loads, NFR B-reads, NKYG*NDY MFMAs
        #pragma unroll 1
        for (int ch = 0; ch < CC; ++ch) {
            const unsigned short* Wc = Wlane + ((size_t)(c0 + ch)*KWG*NKYG)*512;
            const unsigned short* sb = smem + ch*CHSTR;
            #pragma unroll 2
            for (int kxg = 0; kxg < KWG; ++kxg) {
                bfx8 af[NKYG];
                #pragma unroll
                for (int kyg = 0; kyg < NKYG; ++kyg)
                    af[kyg] = *reinterpret_cast<const bfx8*>(Wc + (size_t)(kxg*NKYG + kyg)*512);
                const unsigned short* bp = sb + bcol0 + kxg*4*RSTR;
                bfx8 fr[NFR];
                #pragma unroll
                for (int rg = 0; rg < NFR; ++rg)
                    fr[rg] = *reinterpret_cast<const bfx8*>(bp + rg*8);
                __builtin_amdgcn_s_setprio(1);
                #pragma unroll
                for (int dy = 0; dy < NDY; ++dy)
                    #pragma unroll
                    for (int kyg = 0; kyg < NKYG; ++kyg)
                        acc[dy] = __builtin_amdgcn_mfma_f32_16x16x32_bf16(
                            af[kyg], fr[kyg + dy], acc[dy], 0, 0, 0);
                __builtin_amdgcn_s_setprio(0);
            }
        }
        __syncthreads();
    }
    // ---- epilogue: D row = g*4+r = filter m (sc*N+n), col = lane&15 ----
    const int x = xb*64 + wv*16 + lm;
    #pragma unroll
    for (int dy = 0; dy < NDY; ++dy) {
        int y = y0 + dy*8;
        #pragma unroll
        for (int r = 0; r < 4; ++r) {
            int m  = g*4 + r;
            int sc = m / N;
            int n  = m - sc*N;
            if (sc < 3) {
                size_t oi = ((((size_t)ksp*Btot + b)*N + n)*3 + sc)*((size_t)H*W)
                          + (size_t)y*W + x;
                part[oi] = acc[dy][r];
            }
        }
    }
}

// Sum m3 split-K partials -> out planes 0..2.
__global__ void k_reduce3(const float* __restrict__ part, float* __restrict__ out,
                          int B, int N, int nks) {
    int idx = blockIdx.x*256 + threadIdx.x;
    int tot = B*N*3*128*128;
    if (idx >= tot) return;
    int px = idx & 16383;
    int r = idx >> 14;
    int sc = r % 3; r /= 3;
    int n = r % N; int b = r / N;
    size_t stride = (size_t)B*N*3*16384;
    const float* p = part + ((size_t)(b*N + n)*3 + sc)*16384 + px;
    float s = 0.f;
    for (int ks = 0; ks < nks; ++ks) s += p[(size_t)ks*stride];
    out[(((size_t)(b*N + n)*6 + sc) << 14) + px] = s;
}

// Sum m4 split-K partials + 64->128 bilinear upsample -> out planes 3..5.
__global__ void k_upsample_sum(const float* __restrict__ part, float* __restrict__ out,
                               int B, int N, int nks) {
    int idx = blockIdx.x*256 + threadIdx.x;
    int tot = B*N*3*128*128;
    if (idx >= tot) return;
    int x = idx & 127; int r = idx >> 7;
    int y = r & 127; r >>= 7;
    int sc = r % 3; r /= 3;
    int n = r % N; int b = r / N;
    int y0, y1, x0, x1; float wy, wx;
    bl_w(y, 128, 64, y0, y1, wy);
    bl_w(x, 128, 64, x0, x1, wx);
    size_t stride = (size_t)B*N*3*4096;
    const float* p = part + ((size_t)(b*N + n)*3 + sc)*4096;
    float f00 = 0.f, f10 = 0.f, f01 = 0.f, f11 = 0.f;
    for (int ks = 0; ks < nks; ++ks) {
        const float* q = p + (size_t)ks*stride;
        f00 += q[y0*64 + x0]; f10 += q[y1*64 + x0];
        f01 += q[y0*64 + x1]; f11 += q[y1*64 + x1];
    }
    out[((size_t)((b*N + n)*6 + 3 + sc)*128 + y)*128 + x] =
        (f00*(1.f-wy) + f10*wy)*(1.f-wx) + (f01*(1.f-wy) + f11*wy)*wx;
}

extern "C" void kernel_launch(void* const* d_in, const int* in_sizes, int n_in,
                              void* d_out, int out_size, void* d_ws, size_t ws_size,
                              hipStream_t stream) {
    const float* map3 = (const float*)d_in[0];
    const float* map4 = (const float*)d_in[1];
    const int*   tlbr = (const int*)d_in[2];
    const int*   p_imgh = (const int*)d_in[3];
    const int*   p_imgw = (const int*)d_in[4];
    float* out = (float*)d_out;

    const int C3 = 512, H3 = 128, C4 = 1024, H4 = 64;
    int B = in_sizes[0] / (C3 * H3 * H3);
    int N = in_sizes[2] / (B * 4);
    int ms = 2 + 4 * N + 6;
    const int NKS3 = 8, NKS4 = 32;

    // Workspace: meta (4KB) | part (split-K partials, shared m3/m4) | Wbuf
    char* wsp = (char*)d_ws;
    int* meta = (int*)wsp;
    size_t off = 4096;
    float* part = (float*)(wsp + off);
    size_t part_bytes = (size_t)NKS3 * B * N * 3 * H3 * H3 * 4;  // == m4's NKS4 partials
    off += part_bytes;
    unsigned short* Wbuf = (unsigned short*)(wsp + off);
    size_t wavail = (ws_size > off) ? (ws_size - off) : 0;
    size_t wpb = (size_t)(512/4 * 6 * 3 * 4) * 1024;   // hmm: KT3=512*6*3=9216 -> 9.44MB
    wpb = (size_t)9216 * 1024;
    int cb = (int)(wavail / wpb); if (cb > B) cb = B; if (cb < 1) cb = 1;

    k_meta<<<1, 1, 0, stream>>>(tlbr, p_imgh, p_imgw, B, N, ms, meta);

    { // ---- level 0 (m3): filters -> split-K 8-row conv -> reduce ----
        for (int b0 = 0; b0 < B; b0 += cb) {
            int cbn = (cb < B - b0) ? cb : (B - b0);
            long long pr = (long long)cbn * 9216 * 256;
            k_filters<512,24,24,3><<<(int)((pr + 255) / 256), 256, 0, stream>>>(
                map3, meta, Wbuf, b0, cbn, N, 0, ms, H3, H3);
            dim3 grid(2, 16, cbn * NKS3);
            k_mfconv<512,64,24,24,128,128,3,8,2,88,88,12><<<grid, 256, 0, stream>>>(
                map3, Wbuf, part, b0, B, N, NKS3);
        }
        int tot = B * N * 3 * H3 * H3;
        k_reduce3<<<(tot + 255) / 256, 256, 0, stream>>>(part, out, B, N, NKS3);
    }
    { // ---- level 1 (m4): filters -> split-K 8-row conv -> reduce+upsample ----
        for (int b0 = 0; b0 < B; b0 += cb) {
            int cbn = (cb < B - b0) ? cb : (B - b0);
            long long pr = (long long)cbn * 8192 * 256;
            k_filters<1024,16,16,2><<<(int)((pr + 255) / 256), 256, 0, stream>>>(
                map4, meta, Wbuf, b0, cbn, N, 1, ms, H4, H4);
            dim3 grid(1, 8, cbn * NKS4);
            k_mfconv<1024,32,16,16,64,64,2,8,2,72,80,8><<<grid, 256, 0, stream>>>(
                map4, Wbuf, part, b0, B, N, NKS4);
        }
        int tot = B * N * 3 * H3 * H3;
        k_upsample_sum<<<(tot + 255) / 256, 256, 0, stream>>>(part, out, B, N, NKS4);
    }
}